// Round 17
// baseline (74.583 us; speedup 1.0000x reference)
//
#include <hip/hip_runtime.h>
#include <hip/hip_bf16.h>

#define LPOS 8192
#define HDIM 128
#define M_TOT 4096          // B*Cin
#define GROW  136           // gp row stride (h 0..127, col128 = rowsum, pad to 16B rows)
#define GELEMS (M_TOT * GROW)        // 557056
#define KSPLIT 16
#define CUNITS 1024                  // 16-B units per 64-k chunk
#define BUNITS (4 * CUNITS)          // 4096 units = 65536 B LDS
#define NPART 256

typedef float  f32x4 __attribute__((ext_vector_type(4)));
typedef short  s16x8 __attribute__((ext_vector_type(8)));
typedef unsigned int u32x4 __attribute__((ext_vector_type(4)));

__device__ __forceinline__ unsigned short bf16_rne(float f) {
    unsigned u = __builtin_bit_cast(unsigned, f);
    u += 0x7fffu + ((u >> 16) & 1u);
    return (unsigned short)(u >> 16);
}
__device__ __forceinline__ float bf16f(unsigned short v) {
    return __builtin_bit_cast(float, (unsigned)v << 16);
}

__device__ __forceinline__ s16x8 cvt8(f32x4 a, f32x4 b) {
    s16x8 r;
    r[0] = (short)bf16_rne(a[0]); r[1] = (short)bf16_rne(a[1]);
    r[2] = (short)bf16_rne(a[2]); r[3] = (short)bf16_rne(a[3]);
    r[4] = (short)bf16_rne(b[0]); r[5] = (short)bf16_rne(b[1]);
    r[6] = (short)bf16_rne(b[2]); r[7] = (short)bf16_rne(b[3]);
    return r;
}

__device__ __forceinline__ float sum8(f32x4 a, f32x4 b) {
    return ((a[0] + a[1]) + (a[2] + a[3])) + ((b[0] + b[1]) + (b[2] + b[3]));
}

// ---------------- Kernel 1: SIREN -> h2T; block 0 also inits out & counters --
__global__ __launch_bounds__(256) void k1_siren(
        const float* __restrict__ w1, const float* __restrict__ b1,
        const float* __restrict__ w2, const float* __restrict__ b2,
        const float* __restrict__ bias,
        unsigned short* __restrict__ h2T, float* __restrict__ out,
        unsigned* __restrict__ cnt) {
    __shared__ float w2sT[HDIM * 129];
    __shared__ __align__(16) float h1s[2][HDIM * 8];
    const int tid = threadIdx.x;
    const int s = tid >> 7;
    const int h = tid & 127;

    if (blockIdx.x == 0) {   // init for k3's fixup (stream order: k1 < k3)
        for (int idx = tid; idx < 4096; idx += 256) out[idx] = bias[idx & 63];
        if (tid < 64) cnt[tid] = 0;
    }

    for (int idx = tid; idx < HDIM * HDIM; idx += 256)
        w2sT[(idx & 127) * 129 + (idx >> 7)] = w2[idx];

    const int l0 = blockIdx.x * 16 + s * 8;
    const float myw1 = w1[h], myb1 = b1[h];
    #pragma unroll
    for (int ls = 0; ls < 8; ++ls) {
        float rel = -1.0f + (2.0f / 8191.0f) * (float)(l0 + ls);
        h1s[s][h * 8 + ls] = __sinf(30.0f * (rel * myw1 + myb1));
    }
    __syncthreads();

    const float bb = b2[h];
    float acc[8];
    #pragma unroll
    for (int ls = 0; ls < 8; ++ls) acc[ls] = bb;

    for (int j = 0; j < HDIM; ++j) {
        float wv = w2sT[j * 129 + h];
        const f32x4* hp = (const f32x4*)&h1s[s][j * 8];
        f32x4 p0 = hp[0], p1 = hp[1];
        acc[0] += wv * p0[0]; acc[1] += wv * p0[1];
        acc[2] += wv * p0[2]; acc[3] += wv * p0[3];
        acc[4] += wv * p1[0]; acc[5] += wv * p1[1];
        acc[6] += wv * p1[2]; acc[7] += wv * p1[3];
    }

    u32x4 ov;
    #pragma unroll
    for (int q = 0; q < 4; ++q) {
        unsigned lo = bf16_rne(__sinf(30.0f * acc[2 * q]));
        unsigned hi = bf16_rne(__sinf(30.0f * acc[2 * q + 1]));
        ov[q] = lo | (hi << 16);
    }
    const size_t c = (size_t)(l0 >> 6);
    const int k8 = (l0 >> 3) & 7;
    *(u32x4*)(h2T + (c * CUNITS + (size_t)k8 * 128 + h) * 8) = ov;
}

// ---------------- Kernel 2: partial GEMM (R16 exact) -------------------------
__global__ __launch_bounds__(256, 2) void k2_gemm(
        const float* __restrict__ x, const unsigned short* __restrict__ h2T,
        unsigned short* __restrict__ gp) {
    __shared__ unsigned short lds[BUNITS * 8];     // 65536 B

    const int lane = threadIdx.x & 63;
    const int wv   = threadIdx.x >> 6;
    const int r    = lane & 15;
    const int kg   = lane >> 4;
    const int m0   = blockIdx.x * 128;
    const int y8   = blockIdx.y;                   // 0..15, covers 512 k
    const int kc   = y8 * 512;

    const float* xpa = x + (size_t)(m0 + wv * 32 + r) * LPOS + kc + kg * 8;
    const float* xpb = xpa + 16 * LPOS;

    f32x4 xr[2][2][4];

#define LOADX(SL, IT) do { \
        xr[SL][0][0] = *(const f32x4*)(xpa + (IT) * 64);      \
        xr[SL][0][1] = *(const f32x4*)(xpa + (IT) * 64 + 4);  \
        xr[SL][0][2] = *(const f32x4*)(xpa + (IT) * 64 + 32); \
        xr[SL][0][3] = *(const f32x4*)(xpa + (IT) * 64 + 36); \
        xr[SL][1][0] = *(const f32x4*)(xpb + (IT) * 64);      \
        xr[SL][1][1] = *(const f32x4*)(xpb + (IT) * 64 + 4);  \
        xr[SL][1][2] = *(const f32x4*)(xpb + (IT) * 64 + 32); \
        xr[SL][1][3] = *(const f32x4*)(xpb + (IT) * 64 + 36); \
    } while (0)

    f32x4 acc[2][8];
    #pragma unroll
    for (int s = 0; s < 2; ++s)
        #pragma unroll
        for (int t = 0; t < 8; ++t) { f32x4 z = {0.f,0.f,0.f,0.f}; acc[s][t] = z; }
    float sacc0 = 0.f, sacc1 = 0.f;

    #pragma unroll 1
    for (int g = 0; g < 2; ++g) {
        const int base = g * 4;
        {
            const unsigned short* src = h2T + (size_t)(y8 * 2 + g) * (BUNITS * 8);
            #pragma unroll
            for (int j = 0; j < 16; ++j) {
                const int U = j * 256 + threadIdx.x;
                __builtin_amdgcn_global_load_lds(
                    (const unsigned int*)(src + (size_t)U * 8),
                    (unsigned int*)&lds[U * 8], 16, 0, 0);
            }
        }
        LOADX(0, base); LOADX(1, base + 1);
        __syncthreads();

        #pragma unroll
        for (int it = 0; it < 4; ++it) {
            const int sl = it & 1;
            s16x8 a0lo = cvt8(xr[sl][0][0], xr[sl][0][1]);
            s16x8 a0hi = cvt8(xr[sl][0][2], xr[sl][0][3]);
            s16x8 a1lo = cvt8(xr[sl][1][0], xr[sl][1][1]);
            s16x8 a1hi = cvt8(xr[sl][1][2], xr[sl][1][3]);
            sacc0 += sum8(xr[sl][0][0], xr[sl][0][1]) + sum8(xr[sl][0][2], xr[sl][0][3]);
            sacc1 += sum8(xr[sl][1][0], xr[sl][1][1]) + sum8(xr[sl][1][2], xr[sl][1][3]);
            if (it + 2 < 4) LOADX(sl, base + it + 2);

            #pragma unroll
            for (int t = 0; t < 8; ++t) {
                s16x8 blo = *(const s16x8*)&lds[((size_t)it * CUNITS + kg * 128 + t * 16 + r) * 8];
                s16x8 bhi = *(const s16x8*)&lds[((size_t)it * CUNITS + (kg + 4) * 128 + t * 16 + r) * 8];
                acc[0][t] = __builtin_amdgcn_mfma_f32_16x16x32_bf16(a0lo, blo, acc[0][t], 0, 0, 0);
                acc[0][t] = __builtin_amdgcn_mfma_f32_16x16x32_bf16(a0hi, bhi, acc[0][t], 0, 0, 0);
                acc[1][t] = __builtin_amdgcn_mfma_f32_16x16x32_bf16(a1lo, blo, acc[1][t], 0, 0, 0);
                acc[1][t] = __builtin_amdgcn_mfma_f32_16x16x32_bf16(a1hi, bhi, acc[1][t], 0, 0, 0);
            }
        }
        __syncthreads();
    }
#undef LOADX

    unsigned short* gpy = gp + (size_t)y8 * GELEMS;
    #pragma unroll
    for (int s = 0; s < 2; ++s) {
        #pragma unroll
        for (int t = 0; t < 8; ++t) {
            const int col = t * 16 + r;
            #pragma unroll
            for (int q = 0; q < 4; ++q) {
                const int row = m0 + wv * 32 + s * 16 + kg * 4 + q;
                gpy[(size_t)row * GROW + col] = bf16_rne(acc[s][t][q]);
            }
        }
    }
    sacc0 += __shfl_xor(sacc0, 16); sacc0 += __shfl_xor(sacc0, 32);
    sacc1 += __shfl_xor(sacc1, 16); sacc1 += __shfl_xor(sacc1, 32);
    if (kg == 0) {
        gpy[(size_t)(m0 + wv * 32 + r) * GROW + 128]      = bf16_rne(sacc0);
        gpy[(size_t)(m0 + wv * 32 + 16 + r) * GROW + 128] = bf16_rne(sacc1);
    }
}

// ---------------- Kernel 3: contraction + split-K fixup (k4 folded in) -------
// bid = i*4 + yg. After part stores, arrive on cnt[i] (ACQ_REL, agent); the
// 4th arriver sums the 4 part rows and unsafeAtomicAdds into out (no k4).
__global__ __launch_bounds__(256, 3) void k3_mm(
        const unsigned short* __restrict__ gp, const float* __restrict__ w3,
        const float* __restrict__ b3, float* __restrict__ part,
        float* __restrict__ out, unsigned* __restrict__ cnt) {
    __shared__ unsigned short As[2][64 * 128];   // 2 x 16 KB
    __shared__ unsigned short Bs[64 * 128];      // 16 KB
    __shared__ float b3s[64];
    __shared__ float sls[64];
    __shared__ int is_last;

    const int bid = blockIdx.x;
    const int i   = bid >> 2;
    const int y0  = (bid & 3) * 4;
    const int t    = threadIdx.x;
    const int lane = t & 63;
    const int w    = t >> 6;
    const int r    = lane & 15;
    const int kg   = lane >> 4;

    #pragma unroll
    for (int p = 0; p < 4; ++p) {
        const int row  = p * 16 + (t >> 4);
        const int gran = t & 15;
        const float* src = w3 + (size_t)(row * 64 + i) * HDIM + gran * 8;
        f32x4 v0 = *(const f32x4*)src;
        f32x4 v1 = *(const f32x4*)(src + 4);
        *(s16x8*)&Bs[row * 128 + ((gran ^ (row & 7)) * 8)] = cvt8(v0, v1);
    }
    if (t < 64) b3s[t] = b3[t * 64 + i];

    float sreg = 0.f;
    auto stageA = [&](int y, int d) {
        const unsigned short* src = gp + (size_t)y * GELEMS + (size_t)i * GROW;
        #pragma unroll
        for (int p = 0; p < 4; ++p) {
            const int b    = p * 16 + (t >> 4);
            const int gran = t & 15;
            s16x8 v = *(const s16x8*)(src + (size_t)b * (64 * GROW) + gran * 8);
            *(s16x8*)&As[d][b * 128 + ((gran ^ (b & 7)) * 8)] = v;
        }
        if (t < 64) sreg += bf16f(src[(size_t)t * (64 * GROW) + 128]);
    };

    stageA(y0, 0);
    __syncthreads();

    s16x8 bfr[4][4];
    #pragma unroll
    for (int ct = 0; ct < 4; ++ct) {
        const int o = ct * 16 + r;
        #pragma unroll
        for (int ks = 0; ks < 4; ++ks)
            bfr[ct][ks] = *(const s16x8*)&Bs[o * 128 + (((ks * 4 + kg) ^ (o & 7)) * 8)];
    }

    f32x4 acc[4];
    #pragma unroll
    for (int ct = 0; ct < 4; ++ct) { f32x4 z = {0.f,0.f,0.f,0.f}; acc[ct] = z; }

    const int bA = w * 16 + r;
    #pragma unroll
    for (int yy = 0; yy < 4; ++yy) {
        if (yy + 1 < 4) stageA(y0 + yy + 1, (yy + 1) & 1);
        const unsigned short* buf = &As[yy & 1][0];
        s16x8 af[4];
        #pragma unroll
        for (int ks = 0; ks < 4; ++ks)
            af[ks] = *(const s16x8*)&buf[bA * 128 + (((ks * 4 + kg) ^ (bA & 7)) * 8)];
        #pragma unroll
        for (int ct = 0; ct < 4; ++ct)
            #pragma unroll
            for (int ks = 0; ks < 4; ++ks)
                acc[ct] = __builtin_amdgcn_mfma_f32_16x16x32_bf16(af[ks], bfr[ct][ks], acc[ct], 0, 0, 0);
        __syncthreads();
    }

    if (t < 64) sls[t] = sreg;
    __syncthreads();

    float* po = part + (size_t)bid * 4096;
    #pragma unroll
    for (int ct = 0; ct < 4; ++ct) {
        const int o = ct * 16 + r;
        #pragma unroll
        for (int q = 0; q < 4; ++q) {
            const int b = w * 16 + kg * 4 + q;
            po[b * 64 + o] = acc[ct][q] + sls[b] * b3s[o];
        }
    }

    // ---- split-K fixup: 4th arriver for channel i sums parts into out ----
    __syncthreads();                 // all po stores issued block-wide
    if (t == 0) {
        __threadfence();             // release this block's part writes
        unsigned old = __hip_atomic_fetch_add(&cnt[i], 1u, __ATOMIC_ACQ_REL,
                                              __HIP_MEMORY_SCOPE_AGENT);
        is_last = (old == 3u);
    }
    __syncthreads();
    if (is_last) {
        const float* p0 = part + (size_t)(i * 4 + 0) * 4096;
        const float* p1 = part + (size_t)(i * 4 + 1) * 4096;
        const float* p2 = part + (size_t)(i * 4 + 2) * 4096;
        const float* p3 = part + (size_t)(i * 4 + 3) * 4096;
        #pragma unroll
        for (int n = 0; n < 16; ++n) {
            const int idx = n * 256 + t;
            float s = (p0[idx] + p1[idx]) + (p2[idx] + p3[idx]);
            unsafeAtomicAdd(&out[idx], s);
        }
    }
}

extern "C" void kernel_launch(void* const* d_in, const int* in_sizes, int n_in,
                              void* d_out, int out_size, void* d_ws, size_t ws_size,
                              hipStream_t stream) {
    (void)in_sizes; (void)n_in; (void)out_size; (void)ws_size;
    const float* x    = (const float*)d_in[0];
    const float* w1   = (const float*)d_in[1];
    const float* b1   = (const float*)d_in[2];
    const float* w2   = (const float*)d_in[3];
    const float* b2   = (const float*)d_in[4];
    const float* w3   = (const float*)d_in[5];
    const float* b3   = (const float*)d_in[6];
    const float* bias = (const float*)d_in[7];
    float* out = (float*)d_out;

    char* ws = (char*)d_ws;
    unsigned short* h2T = (unsigned short*)ws;                          // 2.10 MB
    const size_t H2T_BYTES = (size_t)(LPOS / 64) * CUNITS * 16;
    unsigned short* gp = (unsigned short*)(ws + H2T_BYTES);             // 17.8 MB
    const size_t GP_BYTES = (size_t)KSPLIT * GELEMS * 2;
    float* part = (float*)(ws + H2T_BYTES + GP_BYTES);                  // 4 MB
    const size_t PART_BYTES = (size_t)NPART * 4096 * 4;
    unsigned* cnt = (unsigned*)(ws + H2T_BYTES + GP_BYTES + PART_BYTES);

    k1_siren<<<LPOS / 16, 256, 0, stream>>>(w1, b1, w2, b2, bias, h2T, out, cnt);
    k2_gemm<<<dim3(M_TOT / 128, KSPLIT), 256, 0, stream>>>(x, h2T, gp);
    k3_mm<<<NPART, 256, 0, stream>>>(gp, w3, b3, part, out, cnt);
}

// Round 18
// 65.061 us; speedup vs baseline: 1.1463x; 1.1463x over previous
//
#include <hip/hip_runtime.h>
#include <hip/hip_bf16.h>

#define LPOS 8192
#define HDIM 128
#define M_TOT 4096          // B*Cin
#define GROW  136           // gp row stride (h 0..127, col128 = rowsum, pad to 16B rows)
#define GELEMS (M_TOT * GROW)        // 557056
#define KSPLIT 16
#define CUNITS 1024                  // 16-B units per 64-k chunk
#define BUNITS (4 * CUNITS)          // 4096 units = 65536 B LDS
#define NPART 256

typedef float  f32x4 __attribute__((ext_vector_type(4)));
typedef short  s16x8 __attribute__((ext_vector_type(8)));
typedef unsigned int u32x4 __attribute__((ext_vector_type(4)));

__device__ __forceinline__ unsigned short bf16_rne(float f) {
    unsigned u = __builtin_bit_cast(unsigned, f);
    u += 0x7fffu + ((u >> 16) & 1u);
    return (unsigned short)(u >> 16);
}
__device__ __forceinline__ float bf16f(unsigned short v) {
    return __builtin_bit_cast(float, (unsigned)v << 16);
}

__device__ __forceinline__ s16x8 cvt8(f32x4 a, f32x4 b) {
    s16x8 r;
    r[0] = (short)bf16_rne(a[0]); r[1] = (short)bf16_rne(a[1]);
    r[2] = (short)bf16_rne(a[2]); r[3] = (short)bf16_rne(a[3]);
    r[4] = (short)bf16_rne(b[0]); r[5] = (short)bf16_rne(b[1]);
    r[6] = (short)bf16_rne(b[2]); r[7] = (short)bf16_rne(b[3]);
    return r;
}

__device__ __forceinline__ float sum8(f32x4 a, f32x4 b) {
    return ((a[0] + a[1]) + (a[2] + a[3])) + ((b[0] + b[1]) + (b[2] + b[3]));
}

// ---------------- Kernel 1: SIREN -> h2T (R9/R16 exact) ----------------------
__global__ __launch_bounds__(256) void k1_siren(
        const float* __restrict__ w1, const float* __restrict__ b1,
        const float* __restrict__ w2, const float* __restrict__ b2,
        unsigned short* __restrict__ h2T) {
    __shared__ float w2sT[HDIM * 129];
    __shared__ __align__(16) float h1s[2][HDIM * 8];
    const int tid = threadIdx.x;
    const int s = tid >> 7;
    const int h = tid & 127;

    for (int idx = tid; idx < HDIM * HDIM; idx += 256)
        w2sT[(idx & 127) * 129 + (idx >> 7)] = w2[idx];

    const int l0 = blockIdx.x * 16 + s * 8;
    const float myw1 = w1[h], myb1 = b1[h];
    #pragma unroll
    for (int ls = 0; ls < 8; ++ls) {
        float rel = -1.0f + (2.0f / 8191.0f) * (float)(l0 + ls);
        h1s[s][h * 8 + ls] = __sinf(30.0f * (rel * myw1 + myb1));
    }
    __syncthreads();

    const float bb = b2[h];
    float acc[8];
    #pragma unroll
    for (int ls = 0; ls < 8; ++ls) acc[ls] = bb;

    for (int j = 0; j < HDIM; ++j) {
        float wv = w2sT[j * 129 + h];
        const f32x4* hp = (const f32x4*)&h1s[s][j * 8];
        f32x4 p0 = hp[0], p1 = hp[1];
        acc[0] += wv * p0[0]; acc[1] += wv * p0[1];
        acc[2] += wv * p0[2]; acc[3] += wv * p0[3];
        acc[4] += wv * p1[0]; acc[5] += wv * p1[1];
        acc[6] += wv * p1[2]; acc[7] += wv * p1[3];
    }

    u32x4 ov;
    #pragma unroll
    for (int q = 0; q < 4; ++q) {
        unsigned lo = bf16_rne(__sinf(30.0f * acc[2 * q]));
        unsigned hi = bf16_rne(__sinf(30.0f * acc[2 * q + 1]));
        ov[q] = lo | (hi << 16);
    }
    const size_t c = (size_t)(l0 >> 6);
    const int k8 = (l0 >> 3) & 7;
    *(u32x4*)(h2T + (c * CUNITS + (size_t)k8 * 128 + h) * 8) = ov;
}

// ---------------- Kernel 2: partial GEMM (R16 loop; gp in [y][i][b] layout) --
// gp element address: ((i*64 + b)*GROW + col), i = m&63 (channel), b = m>>6.
// Store scatter shape changes but cost is neutral (R10); k3 reads become dense.
__global__ __launch_bounds__(256, 2) void k2_gemm(
        const float* __restrict__ x, const unsigned short* __restrict__ h2T,
        unsigned short* __restrict__ gp) {
    __shared__ unsigned short lds[BUNITS * 8];     // 65536 B

    const int lane = threadIdx.x & 63;
    const int wv   = threadIdx.x >> 6;
    const int r    = lane & 15;
    const int kg   = lane >> 4;
    const int m0   = blockIdx.x * 128;
    const int y8   = blockIdx.y;                   // 0..15, covers 512 k
    const int kc   = y8 * 512;

    const float* xpa = x + (size_t)(m0 + wv * 32 + r) * LPOS + kc + kg * 8;
    const float* xpb = xpa + 16 * LPOS;

    f32x4 xr[2][2][4];

#define LOADX(SL, IT) do { \
        xr[SL][0][0] = *(const f32x4*)(xpa + (IT) * 64);      \
        xr[SL][0][1] = *(const f32x4*)(xpa + (IT) * 64 + 4);  \
        xr[SL][0][2] = *(const f32x4*)(xpa + (IT) * 64 + 32); \
        xr[SL][0][3] = *(const f32x4*)(xpa + (IT) * 64 + 36); \
        xr[SL][1][0] = *(const f32x4*)(xpb + (IT) * 64);      \
        xr[SL][1][1] = *(const f32x4*)(xpb + (IT) * 64 + 4);  \
        xr[SL][1][2] = *(const f32x4*)(xpb + (IT) * 64 + 32); \
        xr[SL][1][3] = *(const f32x4*)(xpb + (IT) * 64 + 36); \
    } while (0)

    f32x4 acc[2][8];
    #pragma unroll
    for (int s = 0; s < 2; ++s)
        #pragma unroll
        for (int t = 0; t < 8; ++t) { f32x4 z = {0.f,0.f,0.f,0.f}; acc[s][t] = z; }
    float sacc0 = 0.f, sacc1 = 0.f;

    #pragma unroll 1
    for (int g = 0; g < 2; ++g) {
        const int base = g * 4;
        {
            const unsigned short* src = h2T + (size_t)(y8 * 2 + g) * (BUNITS * 8);
            #pragma unroll
            for (int j = 0; j < 16; ++j) {
                const int U = j * 256 + threadIdx.x;
                __builtin_amdgcn_global_load_lds(
                    (const unsigned int*)(src + (size_t)U * 8),
                    (unsigned int*)&lds[U * 8], 16, 0, 0);
            }
        }
        LOADX(0, base); LOADX(1, base + 1);
        __syncthreads();

        #pragma unroll
        for (int it = 0; it < 4; ++it) {
            const int sl = it & 1;
            s16x8 a0lo = cvt8(xr[sl][0][0], xr[sl][0][1]);
            s16x8 a0hi = cvt8(xr[sl][0][2], xr[sl][0][3]);
            s16x8 a1lo = cvt8(xr[sl][1][0], xr[sl][1][1]);
            s16x8 a1hi = cvt8(xr[sl][1][2], xr[sl][1][3]);
            sacc0 += sum8(xr[sl][0][0], xr[sl][0][1]) + sum8(xr[sl][0][2], xr[sl][0][3]);
            sacc1 += sum8(xr[sl][1][0], xr[sl][1][1]) + sum8(xr[sl][1][2], xr[sl][1][3]);
            if (it + 2 < 4) LOADX(sl, base + it + 2);

            #pragma unroll
            for (int t = 0; t < 8; ++t) {
                s16x8 blo = *(const s16x8*)&lds[((size_t)it * CUNITS + kg * 128 + t * 16 + r) * 8];
                s16x8 bhi = *(const s16x8*)&lds[((size_t)it * CUNITS + (kg + 4) * 128 + t * 16 + r) * 8];
                acc[0][t] = __builtin_amdgcn_mfma_f32_16x16x32_bf16(a0lo, blo, acc[0][t], 0, 0, 0);
                acc[0][t] = __builtin_amdgcn_mfma_f32_16x16x32_bf16(a0hi, bhi, acc[0][t], 0, 0, 0);
                acc[1][t] = __builtin_amdgcn_mfma_f32_16x16x32_bf16(a1lo, blo, acc[1][t], 0, 0, 0);
                acc[1][t] = __builtin_amdgcn_mfma_f32_16x16x32_bf16(a1hi, bhi, acc[1][t], 0, 0, 0);
            }
        }
        __syncthreads();
    }
#undef LOADX

    unsigned short* gpy = gp + (size_t)y8 * GELEMS;
    #pragma unroll
    for (int s = 0; s < 2; ++s) {
        #pragma unroll
        for (int t = 0; t < 8; ++t) {
            const int col = t * 16 + r;
            #pragma unroll
            for (int q = 0; q < 4; ++q) {
                const int row = m0 + wv * 32 + s * 16 + kg * 4 + q;
                const int ii = row & 63, bb2 = row >> 6;
                gpy[((size_t)ii * 64 + bb2) * GROW + col] = bf16_rne(acc[s][t][q]);
            }
        }
    }
    sacc0 += __shfl_xor(sacc0, 16); sacc0 += __shfl_xor(sacc0, 32);
    sacc1 += __shfl_xor(sacc1, 16); sacc1 += __shfl_xor(sacc1, 32);
    if (kg == 0) {
        const int rowA = m0 + wv * 32 + r;
        const int rowB = rowA + 16;
        gpy[((size_t)(rowA & 63) * 64 + (rowA >> 6)) * GROW + 128] = bf16_rne(sacc0);
        gpy[((size_t)(rowB & 63) * 64 + (rowB >> 6)) * GROW + 128] = bf16_rne(sacc1);
    }
}

// ---------------- Kernel 3: per-i contraction; gp reads now DENSE ------------
// bid = i*4 + yg (256 blocks); stageA reads gp[y][i][b][*]: 256 B contiguous
// per b-row, 16 lanes per row -> near-perfect sector efficiency.
__global__ __launch_bounds__(256, 3) void k3_mm(
        const unsigned short* __restrict__ gp, const float* __restrict__ w3,
        const float* __restrict__ b3, float* __restrict__ part) {
    __shared__ unsigned short As[2][64 * 128];   // 2 x 16 KB
    __shared__ unsigned short Bs[64 * 128];      // 16 KB
    __shared__ float b3s[64];
    __shared__ float sls[64];

    const int bid = blockIdx.x;
    const int i   = bid >> 2;
    const int y0  = (bid & 3) * 4;
    const int t    = threadIdx.x;
    const int lane = t & 63;
    const int w    = t >> 6;
    const int r    = lane & 15;
    const int kg   = lane >> 4;

    #pragma unroll
    for (int p = 0; p < 4; ++p) {
        const int row  = p * 16 + (t >> 4);
        const int gran = t & 15;
        const float* src = w3 + (size_t)(row * 64 + i) * HDIM + gran * 8;
        f32x4 v0 = *(const f32x4*)src;
        f32x4 v1 = *(const f32x4*)(src + 4);
        *(s16x8*)&Bs[row * 128 + ((gran ^ (row & 7)) * 8)] = cvt8(v0, v1);
    }
    if (t < 64) b3s[t] = b3[t * 64 + i];

    float sreg = 0.f;
    auto stageA = [&](int y, int d) {
        const unsigned short* src = gp + (size_t)y * GELEMS + (size_t)i * (64 * GROW);
        #pragma unroll
        for (int p = 0; p < 4; ++p) {
            const int b    = p * 16 + (t >> 4);
            const int gran = t & 15;
            s16x8 v = *(const s16x8*)(src + (size_t)b * GROW + gran * 8);
            *(s16x8*)&As[d][b * 128 + ((gran ^ (b & 7)) * 8)] = v;
        }
        if (t < 64) sreg += bf16f(src[(size_t)t * GROW + 128]);
    };

    stageA(y0, 0);
    __syncthreads();

    s16x8 bfr[4][4];
    #pragma unroll
    for (int ct = 0; ct < 4; ++ct) {
        const int o = ct * 16 + r;
        #pragma unroll
        for (int ks = 0; ks < 4; ++ks)
            bfr[ct][ks] = *(const s16x8*)&Bs[o * 128 + (((ks * 4 + kg) ^ (o & 7)) * 8)];
    }

    f32x4 acc[4];
    #pragma unroll
    for (int ct = 0; ct < 4; ++ct) { f32x4 z = {0.f,0.f,0.f,0.f}; acc[ct] = z; }

    const int bA = w * 16 + r;
    #pragma unroll
    for (int yy = 0; yy < 4; ++yy) {
        if (yy + 1 < 4) stageA(y0 + yy + 1, (yy + 1) & 1);
        const unsigned short* buf = &As[yy & 1][0];
        s16x8 af[4];
        #pragma unroll
        for (int ks = 0; ks < 4; ++ks)
            af[ks] = *(const s16x8*)&buf[bA * 128 + (((ks * 4 + kg) ^ (bA & 7)) * 8)];
        #pragma unroll
        for (int ct = 0; ct < 4; ++ct)
            #pragma unroll
            for (int ks = 0; ks < 4; ++ks)
                acc[ct] = __builtin_amdgcn_mfma_f32_16x16x32_bf16(af[ks], bfr[ct][ks], acc[ct], 0, 0, 0);
        __syncthreads();
    }

    if (t < 64) sls[t] = sreg;
    __syncthreads();

    float* po = part + (size_t)bid * 4096;
    #pragma unroll
    for (int ct = 0; ct < 4; ++ct) {
        const int o = ct * 16 + r;
        #pragma unroll
        for (int q = 0; q < 4; ++q) {
            const int b = w * 16 + kg * 4 + q;
            po[b * 64 + o] = acc[ct][q] + sls[b] * b3s[o];
        }
    }
}

// ---------------- Kernel 4: out[idx] = bias[idx&63] + sum_p part[p][idx] -----
__global__ __launch_bounds__(256) void k4_final(
        const float* __restrict__ part, const float* __restrict__ bias,
        float* __restrict__ out) {
    const int idx = blockIdx.x * 256 + threadIdx.x;
    float s = bias[idx & 63];
    #pragma unroll 8
    for (int p = 0; p < NPART; ++p)
        s += part[(size_t)p * 4096 + idx];
    out[idx] = s;
}

extern "C" void kernel_launch(void* const* d_in, const int* in_sizes, int n_in,
                              void* d_out, int out_size, void* d_ws, size_t ws_size,
                              hipStream_t stream) {
    (void)in_sizes; (void)n_in; (void)out_size; (void)ws_size;
    const float* x    = (const float*)d_in[0];
    const float* w1   = (const float*)d_in[1];
    const float* b1   = (const float*)d_in[2];
    const float* w2   = (const float*)d_in[3];
    const float* b2   = (const float*)d_in[4];
    const float* w3   = (const float*)d_in[5];
    const float* b3   = (const float*)d_in[6];
    const float* bias = (const float*)d_in[7];
    float* out = (float*)d_out;

    char* ws = (char*)d_ws;
    unsigned short* h2T = (unsigned short*)ws;                          // 2.10 MB
    const size_t H2T_BYTES = (size_t)(LPOS / 64) * CUNITS * 16;
    unsigned short* gp = (unsigned short*)(ws + H2T_BYTES);             // 17.8 MB
    const size_t GP_BYTES = (size_t)KSPLIT * GELEMS * 2;
    float* part = (float*)(ws + H2T_BYTES + GP_BYTES);                  // 4 MB

    k1_siren<<<LPOS / 16, 256, 0, stream>>>(w1, b1, w2, b2, h2T);
    k2_gemm<<<dim3(M_TOT / 128, KSPLIT), 256, 0, stream>>>(x, h2T, gp);
    k3_mm<<<NPART, 256, 0, stream>>>(gp, w3, b3, part);
    k4_final<<<16, 256, 0, stream>>>(part, bias, out);
}

// Round 19
// 62.004 us; speedup vs baseline: 1.2029x; 1.0493x over previous
//
#include <hip/hip_runtime.h>
#include <hip/hip_bf16.h>

#define LPOS 8192
#define HDIM 128
#define M_TOT 4096          // B*Cin
#define GROW  136           // gp row stride (h 0..127, col128 = rowsum, pad to 16B rows)
#define GELEMS (M_TOT * GROW)        // 557056
#define KSPLIT 16
#define CUNITS 1024                  // 16-B units per 64-k chunk
#define BUNITS (4 * CUNITS)          // 4096 units = 65536 B LDS
#define NPART 256

typedef float  f32x4 __attribute__((ext_vector_type(4)));
typedef short  s16x8 __attribute__((ext_vector_type(8)));
typedef unsigned int u32x4 __attribute__((ext_vector_type(4)));

__device__ __forceinline__ unsigned short bf16_rne(float f) {
    unsigned u = __builtin_bit_cast(unsigned, f);
    u += 0x7fffu + ((u >> 16) & 1u);
    return (unsigned short)(u >> 16);
}
__device__ __forceinline__ float bf16f(unsigned short v) {
    return __builtin_bit_cast(float, (unsigned)v << 16);
}

__device__ __forceinline__ s16x8 cvt8(f32x4 a, f32x4 b) {
    s16x8 r;
    r[0] = (short)bf16_rne(a[0]); r[1] = (short)bf16_rne(a[1]);
    r[2] = (short)bf16_rne(a[2]); r[3] = (short)bf16_rne(a[3]);
    r[4] = (short)bf16_rne(b[0]); r[5] = (short)bf16_rne(b[1]);
    r[6] = (short)bf16_rne(b[2]); r[7] = (short)bf16_rne(b[3]);
    return r;
}

__device__ __forceinline__ float sum8(f32x4 a, f32x4 b) {
    return ((a[0] + a[1]) + (a[2] + a[3])) + ((b[0] + b[1]) + (b[2] + b[3]));
}

// ---------------- Kernel 1: SIREN -> h2T (R18 exact) -------------------------
__global__ __launch_bounds__(256) void k1_siren(
        const float* __restrict__ w1, const float* __restrict__ b1,
        const float* __restrict__ w2, const float* __restrict__ b2,
        unsigned short* __restrict__ h2T) {
    __shared__ float w2sT[HDIM * 129];
    __shared__ __align__(16) float h1s[2][HDIM * 8];
    const int tid = threadIdx.x;
    const int s = tid >> 7;
    const int h = tid & 127;

    for (int idx = tid; idx < HDIM * HDIM; idx += 256)
        w2sT[(idx & 127) * 129 + (idx >> 7)] = w2[idx];

    const int l0 = blockIdx.x * 16 + s * 8;
    const float myw1 = w1[h], myb1 = b1[h];
    #pragma unroll
    for (int ls = 0; ls < 8; ++ls) {
        float rel = -1.0f + (2.0f / 8191.0f) * (float)(l0 + ls);
        h1s[s][h * 8 + ls] = __sinf(30.0f * (rel * myw1 + myb1));
    }
    __syncthreads();

    const float bb = b2[h];
    float acc[8];
    #pragma unroll
    for (int ls = 0; ls < 8; ++ls) acc[ls] = bb;

    for (int j = 0; j < HDIM; ++j) {
        float wv = w2sT[j * 129 + h];
        const f32x4* hp = (const f32x4*)&h1s[s][j * 8];
        f32x4 p0 = hp[0], p1 = hp[1];
        acc[0] += wv * p0[0]; acc[1] += wv * p0[1];
        acc[2] += wv * p0[2]; acc[3] += wv * p0[3];
        acc[4] += wv * p1[0]; acc[5] += wv * p1[1];
        acc[6] += wv * p1[2]; acc[7] += wv * p1[3];
    }

    u32x4 ov;
    #pragma unroll
    for (int q = 0; q < 4; ++q) {
        unsigned lo = bf16_rne(__sinf(30.0f * acc[2 * q]));
        unsigned hi = bf16_rne(__sinf(30.0f * acc[2 * q + 1]));
        ov[q] = lo | (hi << 16);
    }
    const size_t c = (size_t)(l0 >> 6);
    const int k8 = (l0 >> 3) & 7;
    *(u32x4*)(h2T + (c * CUNITS + (size_t)k8 * 128 + h) * 8) = ov;
}

// ---------------- Kernel 2: partial GEMM (R18 exact; [y][i][b] gp layout) ----
__global__ __launch_bounds__(256, 2) void k2_gemm(
        const float* __restrict__ x, const unsigned short* __restrict__ h2T,
        unsigned short* __restrict__ gp) {
    __shared__ unsigned short lds[BUNITS * 8];     // 65536 B

    const int lane = threadIdx.x & 63;
    const int wv   = threadIdx.x >> 6;
    const int r    = lane & 15;
    const int kg   = lane >> 4;
    const int m0   = blockIdx.x * 128;
    const int y8   = blockIdx.y;                   // 0..15, covers 512 k
    const int kc   = y8 * 512;

    const float* xpa = x + (size_t)(m0 + wv * 32 + r) * LPOS + kc + kg * 8;
    const float* xpb = xpa + 16 * LPOS;

    f32x4 xr[2][2][4];

#define LOADX(SL, IT) do { \
        xr[SL][0][0] = *(const f32x4*)(xpa + (IT) * 64);      \
        xr[SL][0][1] = *(const f32x4*)(xpa + (IT) * 64 + 4);  \
        xr[SL][0][2] = *(const f32x4*)(xpa + (IT) * 64 + 32); \
        xr[SL][0][3] = *(const f32x4*)(xpa + (IT) * 64 + 36); \
        xr[SL][1][0] = *(const f32x4*)(xpb + (IT) * 64);      \
        xr[SL][1][1] = *(const f32x4*)(xpb + (IT) * 64 + 4);  \
        xr[SL][1][2] = *(const f32x4*)(xpb + (IT) * 64 + 32); \
        xr[SL][1][3] = *(const f32x4*)(xpb + (IT) * 64 + 36); \
    } while (0)

    f32x4 acc[2][8];
    #pragma unroll
    for (int s = 0; s < 2; ++s)
        #pragma unroll
        for (int t = 0; t < 8; ++t) { f32x4 z = {0.f,0.f,0.f,0.f}; acc[s][t] = z; }
    float sacc0 = 0.f, sacc1 = 0.f;

    #pragma unroll 1
    for (int g = 0; g < 2; ++g) {
        const int base = g * 4;
        {
            const unsigned short* src = h2T + (size_t)(y8 * 2 + g) * (BUNITS * 8);
            #pragma unroll
            for (int j = 0; j < 16; ++j) {
                const int U = j * 256 + threadIdx.x;
                __builtin_amdgcn_global_load_lds(
                    (const unsigned int*)(src + (size_t)U * 8),
                    (unsigned int*)&lds[U * 8], 16, 0, 0);
            }
        }
        LOADX(0, base); LOADX(1, base + 1);
        __syncthreads();

        #pragma unroll
        for (int it = 0; it < 4; ++it) {
            const int sl = it & 1;
            s16x8 a0lo = cvt8(xr[sl][0][0], xr[sl][0][1]);
            s16x8 a0hi = cvt8(xr[sl][0][2], xr[sl][0][3]);
            s16x8 a1lo = cvt8(xr[sl][1][0], xr[sl][1][1]);
            s16x8 a1hi = cvt8(xr[sl][1][2], xr[sl][1][3]);
            sacc0 += sum8(xr[sl][0][0], xr[sl][0][1]) + sum8(xr[sl][0][2], xr[sl][0][3]);
            sacc1 += sum8(xr[sl][1][0], xr[sl][1][1]) + sum8(xr[sl][1][2], xr[sl][1][3]);
            if (it + 2 < 4) LOADX(sl, base + it + 2);

            #pragma unroll
            for (int t = 0; t < 8; ++t) {
                s16x8 blo = *(const s16x8*)&lds[((size_t)it * CUNITS + kg * 128 + t * 16 + r) * 8];
                s16x8 bhi = *(const s16x8*)&lds[((size_t)it * CUNITS + (kg + 4) * 128 + t * 16 + r) * 8];
                acc[0][t] = __builtin_amdgcn_mfma_f32_16x16x32_bf16(a0lo, blo, acc[0][t], 0, 0, 0);
                acc[0][t] = __builtin_amdgcn_mfma_f32_16x16x32_bf16(a0hi, bhi, acc[0][t], 0, 0, 0);
                acc[1][t] = __builtin_amdgcn_mfma_f32_16x16x32_bf16(a1lo, blo, acc[1][t], 0, 0, 0);
                acc[1][t] = __builtin_amdgcn_mfma_f32_16x16x32_bf16(a1hi, bhi, acc[1][t], 0, 0, 0);
            }
        }
        __syncthreads();
    }
#undef LOADX

    unsigned short* gpy = gp + (size_t)y8 * GELEMS;
    #pragma unroll
    for (int s = 0; s < 2; ++s) {
        #pragma unroll
        for (int t = 0; t < 8; ++t) {
            const int col = t * 16 + r;
            #pragma unroll
            for (int q = 0; q < 4; ++q) {
                const int row = m0 + wv * 32 + s * 16 + kg * 4 + q;
                const int ii = row & 63, bb2 = row >> 6;
                gpy[((size_t)ii * 64 + bb2) * GROW + col] = bf16_rne(acc[s][t][q]);
            }
        }
    }
    sacc0 += __shfl_xor(sacc0, 16); sacc0 += __shfl_xor(sacc0, 32);
    sacc1 += __shfl_xor(sacc1, 16); sacc1 += __shfl_xor(sacc1, 32);
    if (kg == 0) {
        const int rowA = m0 + wv * 32 + r;
        const int rowB = rowA + 16;
        gpy[((size_t)(rowA & 63) * 64 + (rowA >> 6)) * GROW + 128] = bf16_rne(sacc0);
        gpy[((size_t)(rowB & 63) * 64 + (rowB >> 6)) * GROW + 128] = bf16_rne(sacc1);
    }
}

// ---------------- Kernel 3: contraction; T14 async-STAGE, 3-buffer -----------
// bid = i*4 + yg (256 blocks = 1/CU). Loads for y+2 issued in iter y, ds_write
// in iter y+1 -> HBM/L3 latency spans a full compute phase. 3 barriers total.
__global__ __launch_bounds__(256) void k3_mm(
        const unsigned short* __restrict__ gp, const float* __restrict__ w3,
        const float* __restrict__ b3, float* __restrict__ part) {
    __shared__ unsigned short As[3][64 * 128];   // 3 x 16 KB
    __shared__ unsigned short Bs[64 * 128];      // 16 KB
    __shared__ float b3s[64];
    __shared__ float sls[64];

    const int bid = blockIdx.x;
    const int i   = bid >> 2;
    const int y0  = (bid & 3) * 4;
    const int t    = threadIdx.x;
    const int lane = t & 63;
    const int w    = t >> 6;
    const int r    = lane & 15;
    const int kg   = lane >> 4;
    const int bbr  = t >> 4;        // staging row group
    const int gran = t & 15;

    #pragma unroll
    for (int p = 0; p < 4; ++p) {
        const int row = p * 16 + bbr;
        const float* src = w3 + (size_t)(row * 64 + i) * HDIM + gran * 8;
        f32x4 v0 = *(const f32x4*)src;
        f32x4 v1 = *(const f32x4*)(src + 4);
        *(s16x8*)&Bs[row * 128 + ((gran ^ (row & 7)) * 8)] = cvt8(v0, v1);
    }
    if (t < 64) b3s[t] = b3[t * 64 + i];

    float sreg = 0.f;
    const unsigned short* gpi = gp + (size_t)i * (64 * GROW);

    s16x8 va[4]; unsigned short ra = 0;
    s16x8 vb[4]; unsigned short rb = 0;

#define ISSUE(Y, V, R_) do { \
        const unsigned short* src_ = gpi + (size_t)(Y) * GELEMS; \
        _Pragma("unroll") for (int p_ = 0; p_ < 4; ++p_) \
            V[p_] = *(const s16x8*)(src_ + (size_t)(p_ * 16 + bbr) * GROW + gran * 8); \
        if (t < 64) R_ = src_[(size_t)t * GROW + 128]; \
    } while (0)

#define WRITE(D, V, R_) do { \
        _Pragma("unroll") for (int p_ = 0; p_ < 4; ++p_) { \
            const int row_ = p_ * 16 + bbr; \
            *(s16x8*)&As[D][row_ * 128 + ((gran ^ (row_ & 7)) * 8)] = V[p_]; } \
        if (t < 64) sreg += bf16f(R_); \
    } while (0)

    // prologue: buffers 0,1 staged; loads for y0+2 left in flight
    ISSUE(y0, va, ra);     WRITE(0, va, ra);
    ISSUE(y0 + 1, vb, rb); WRITE(1, vb, rb);
    ISSUE(y0 + 2, va, ra);
    __syncthreads();

    s16x8 bfr[4][4];
    #pragma unroll
    for (int ct = 0; ct < 4; ++ct) {
        const int o = ct * 16 + r;
        #pragma unroll
        for (int ks = 0; ks < 4; ++ks)
            bfr[ct][ks] = *(const s16x8*)&Bs[o * 128 + (((ks * 4 + kg) ^ (o & 7)) * 8)];
    }

    f32x4 acc[4];
    #pragma unroll
    for (int ct = 0; ct < 4; ++ct) { f32x4 z = {0.f,0.f,0.f,0.f}; acc[ct] = z; }

    const int bA = w * 16 + r;
#define COMPUTE(D) do { \
        const unsigned short* buf_ = &As[D][0]; \
        s16x8 af_[4]; \
        _Pragma("unroll") for (int ks = 0; ks < 4; ++ks) \
            af_[ks] = *(const s16x8*)&buf_[bA * 128 + (((ks * 4 + kg) ^ (bA & 7)) * 8)]; \
        _Pragma("unroll") for (int ct = 0; ct < 4; ++ct) \
            _Pragma("unroll") for (int ks = 0; ks < 4; ++ks) \
                acc[ct] = __builtin_amdgcn_mfma_f32_16x16x32_bf16(af_[ks], bfr[ct][ks], acc[ct], 0, 0, 0); \
    } while (0)

    // yy=0: compute buf0; land y0+2 into buf2; issue y0+3
    COMPUTE(0);
    WRITE(2, va, ra);
    ISSUE(y0 + 3, vb, rb);
    __syncthreads();
    // yy=1: compute buf1; land y0+3 into buf0 (done with it since yy=0 barrier)
    COMPUTE(1);
    WRITE(0, vb, rb);
    __syncthreads();
    // yy=2, yy=3 (no more writes -> no barrier between)
    COMPUTE(2);
    COMPUTE(0);

#undef COMPUTE
#undef WRITE
#undef ISSUE

    if (t < 64) sls[t] = sreg;
    __syncthreads();

    float* po = part + (size_t)bid * 4096;
    #pragma unroll
    for (int ct = 0; ct < 4; ++ct) {
        const int o = ct * 16 + r;
        #pragma unroll
        for (int q = 0; q < 4; ++q) {
            const int b = w * 16 + kg * 4 + q;
            po[b * 64 + o] = acc[ct][q] + sls[b] * b3s[o];
        }
    }
}

// ---------------- Kernel 4: wide final reduce (64 blocks x 256 thr) ----------
// thread (il = t&63, pg = t>>6): sums 64 partials for idx = bid*64+il;
// LDS reduce over the 4 p-groups.
__global__ __launch_bounds__(256) void k4_final(
        const float* __restrict__ part, const float* __restrict__ bias,
        float* __restrict__ out) {
    __shared__ float red[4][64];
    const int t  = threadIdx.x;
    const int il = t & 63;
    const int pg = t >> 6;
    const int idx = blockIdx.x * 64 + il;

    float s = 0.f;
    #pragma unroll 8
    for (int p = pg * 64; p < pg * 64 + 64; ++p)
        s += part[(size_t)p * 4096 + idx];
    red[pg][il] = s;
    __syncthreads();
    if (t < 64)
        out[blockIdx.x * 64 + t] = bias[t] + ((red[0][t] + red[1][t]) + (red[2][t] + red[3][t]));
}

extern "C" void kernel_launch(void* const* d_in, const int* in_sizes, int n_in,
                              void* d_out, int out_size, void* d_ws, size_t ws_size,
                              hipStream_t stream) {
    (void)in_sizes; (void)n_in; (void)out_size; (void)ws_size;
    const float* x    = (const float*)d_in[0];
    const float* w1   = (const float*)d_in[1];
    const float* b1   = (const float*)d_in[2];
    const float* w2   = (const float*)d_in[3];
    const float* b2   = (const float*)d_in[4];
    const float* w3   = (const float*)d_in[5];
    const float* b3   = (const float*)d_in[6];
    const float* bias = (const float*)d_in[7];
    float* out = (float*)d_out;

    char* ws = (char*)d_ws;
    unsigned short* h2T = (unsigned short*)ws;                          // 2.10 MB
    const size_t H2T_BYTES = (size_t)(LPOS / 64) * CUNITS * 16;
    unsigned short* gp = (unsigned short*)(ws + H2T_BYTES);             // 17.8 MB
    const size_t GP_BYTES = (size_t)KSPLIT * GELEMS * 2;
    float* part = (float*)(ws + H2T_BYTES + GP_BYTES);                  // 4 MB

    k1_siren<<<LPOS / 16, 256, 0, stream>>>(w1, b1, w2, b2, h2T);
    k2_gemm<<<dim3(M_TOT / 128, KSPLIT), 256, 0, stream>>>(x, h2T, gp);
    k3_mm<<<NPART, 256, 0, stream>>>(gp, w3, b3, part);
    k4_final<<<64, 256, 0, stream>>>(part, bias, out);
}

// Round 20
// 59.893 us; speedup vs baseline: 1.2453x; 1.0352x over previous
//
#include <hip/hip_runtime.h>
#include <hip/hip_bf16.h>

#define LPOS 8192
#define HDIM 128
#define M_TOT 4096          // B*Cin
#define KSPLIT 16
#define CUNITS 1024                  // 16-B units per 64-k chunk
#define BUNITS (4 * CUNITS)          // 4096 units = 65536 B LDS
#define NPART 1024                   // 64 i x 16 y partials

typedef float  f32x4 __attribute__((ext_vector_type(4)));
typedef short  s16x8 __attribute__((ext_vector_type(8)));
typedef unsigned int u32x4 __attribute__((ext_vector_type(4)));

__device__ __forceinline__ unsigned short bf16_rne(float f) {
    unsigned u = __builtin_bit_cast(unsigned, f);
    u += 0x7fffu + ((u >> 16) & 1u);
    return (unsigned short)(u >> 16);
}

__device__ __forceinline__ s16x8 cvt8(f32x4 a, f32x4 b) {
    s16x8 r;
    r[0] = (short)bf16_rne(a[0]); r[1] = (short)bf16_rne(a[1]);
    r[2] = (short)bf16_rne(a[2]); r[3] = (short)bf16_rne(a[3]);
    r[4] = (short)bf16_rne(b[0]); r[5] = (short)bf16_rne(b[1]);
    r[6] = (short)bf16_rne(b[2]); r[7] = (short)bf16_rne(b[3]);
    return r;
}

__device__ __forceinline__ float sum8(f32x4 a, f32x4 b) {
    return ((a[0] + a[1]) + (a[2] + a[3])) + ((b[0] + b[1]) + (b[2] + b[3]));
}

// ---------------- Kernel 1: SIREN -> h2T (R19 exact) -------------------------
__global__ __launch_bounds__(256) void k1_siren(
        const float* __restrict__ w1, const float* __restrict__ b1,
        const float* __restrict__ w2, const float* __restrict__ b2,
        unsigned short* __restrict__ h2T) {
    __shared__ float w2sT[HDIM * 129];
    __shared__ __align__(16) float h1s[2][HDIM * 8];
    const int tid = threadIdx.x;
    const int s = tid >> 7;
    const int h = tid & 127;

    for (int idx = tid; idx < HDIM * HDIM; idx += 256)
        w2sT[(idx & 127) * 129 + (idx >> 7)] = w2[idx];

    const int l0 = blockIdx.x * 16 + s * 8;
    const float myw1 = w1[h], myb1 = b1[h];
    #pragma unroll
    for (int ls = 0; ls < 8; ++ls) {
        float rel = -1.0f + (2.0f / 8191.0f) * (float)(l0 + ls);
        h1s[s][h * 8 + ls] = __sinf(30.0f * (rel * myw1 + myb1));
    }
    __syncthreads();

    const float bb = b2[h];
    float acc[8];
    #pragma unroll
    for (int ls = 0; ls < 8; ++ls) acc[ls] = bb;

    for (int j = 0; j < HDIM; ++j) {
        float wv = w2sT[j * 129 + h];
        const f32x4* hp = (const f32x4*)&h1s[s][j * 8];
        f32x4 p0 = hp[0], p1 = hp[1];
        acc[0] += wv * p0[0]; acc[1] += wv * p0[1];
        acc[2] += wv * p0[2]; acc[3] += wv * p0[3];
        acc[4] += wv * p1[0]; acc[5] += wv * p1[1];
        acc[6] += wv * p1[2]; acc[7] += wv * p1[3];
    }

    u32x4 ov;
    #pragma unroll
    for (int q = 0; q < 4; ++q) {
        unsigned lo = bf16_rne(__sinf(30.0f * acc[2 * q]));
        unsigned hi = bf16_rne(__sinf(30.0f * acc[2 * q + 1]));
        ov[q] = lo | (hi << 16);
    }
    const size_t c = (size_t)(l0 >> 6);
    const int k8 = (l0 >> 3) & 7;
    *(u32x4*)(h2T + (c * CUNITS + (size_t)k8 * 128 + h) * 8) = ov;
}

// ---------------- Kernel 2: per-channel GEMM + fused contraction -------------
// Block (i, y8): rows m = b*64+i (b=0..63), K-chunk 512. Main loop = R16 shape
// with M=64 (each wave 16 b-rows). Epilogue: G[64b x 128h] -> LDS (bf16, k3's
// swizzle), w3[o*64+i] -> LDS, then k3's verbatim 16-MFMA contraction; writes
// part[(i*16+y8)][b*64+o]. gp buffer and k3 kernel are GONE.
__global__ __launch_bounds__(256, 2) void k2_fused(
        const float* __restrict__ x, const unsigned short* __restrict__ h2T,
        const float* __restrict__ w3, const float* __restrict__ b3,
        float* __restrict__ part) {
    __shared__ __align__(16) char smem[65536];
    unsigned short* lds = (unsigned short*)smem;   // B-stage 64 KB (main loop)

    const int t    = threadIdx.x;
    const int lane = t & 63;
    const int wv   = t >> 6;
    const int r    = lane & 15;
    const int kg   = lane >> 4;
    const int i    = blockIdx.x;     // channel 0..63
    const int y8   = blockIdx.y;     // 0..15
    const int kc   = y8 * 512;

    // x row for A-frags: b = wv*16 + r
    const float* xp = x + (size_t)((wv * 16 + r) * 64 + i) * LPOS + kc + kg * 8;

    f32x4 xr[2][4];
#define LOADX(SL, IT) do { \
        xr[SL][0] = *(const f32x4*)(xp + (IT) * 64);      \
        xr[SL][1] = *(const f32x4*)(xp + (IT) * 64 + 4);  \
        xr[SL][2] = *(const f32x4*)(xp + (IT) * 64 + 32); \
        xr[SL][3] = *(const f32x4*)(xp + (IT) * 64 + 36); \
    } while (0)

    f32x4 acc[8];
    #pragma unroll
    for (int t8 = 0; t8 < 8; ++t8) { f32x4 z = {0.f,0.f,0.f,0.f}; acc[t8] = z; }
    float sacc = 0.f;

    #pragma unroll 1
    for (int g = 0; g < 2; ++g) {
        const int base = g * 4;
        {   // stage B chunk-group g (64 KB)
            const unsigned short* src = h2T + (size_t)(y8 * 2 + g) * (BUNITS * 8);
            #pragma unroll
            for (int j = 0; j < 16; ++j) {
                const int U = j * 256 + t;
                __builtin_amdgcn_global_load_lds(
                    (const unsigned int*)(src + (size_t)U * 8),
                    (unsigned int*)&lds[U * 8], 16, 0, 0);
            }
        }
        LOADX(0, base); LOADX(1, base + 1);
        __syncthreads();

        #pragma unroll
        for (int it = 0; it < 4; ++it) {
            const int sl = it & 1;
            s16x8 alo = cvt8(xr[sl][0], xr[sl][1]);
            s16x8 ahi = cvt8(xr[sl][2], xr[sl][3]);
            sacc += sum8(xr[sl][0], xr[sl][1]) + sum8(xr[sl][2], xr[sl][3]);
            if (it + 2 < 4) LOADX(sl, base + it + 2);

            #pragma unroll
            for (int t8 = 0; t8 < 8; ++t8) {
                s16x8 blo = *(const s16x8*)&lds[((size_t)it * CUNITS + kg * 128 + t8 * 16 + r) * 8];
                s16x8 bhi = *(const s16x8*)&lds[((size_t)it * CUNITS + (kg + 4) * 128 + t8 * 16 + r) * 8];
                acc[t8] = __builtin_amdgcn_mfma_f32_16x16x32_bf16(alo, blo, acc[t8], 0, 0, 0);
                acc[t8] = __builtin_amdgcn_mfma_f32_16x16x32_bf16(ahi, bhi, acc[t8], 0, 0, 0);
            }
        }
        __syncthreads();   // B(g) reads done; next g restages (or epilogue reuses)
    }
#undef LOADX

    // ---------------- epilogue: contraction over h inside the block ----------
    unsigned short* As = (unsigned short*)smem;            // [64][128] bf16 swz
    unsigned short* Bs = (unsigned short*)(smem + 16384);  // w3 [64o][128h] swz
    float* b3s = (float*)(smem + 32768);                   // 64 f32
    float* sls = (float*)(smem + 33024);                   // 64 f32

    // G -> As: C/D layout col = t8*16+r, row(b) = wv*16 + kg*4 + q.
    // Store logical granule cg of row b at position cg^(b&7) (inverts k3 read).
    #pragma unroll
    for (int t8 = 0; t8 < 8; ++t8) {
        const int col = t8 * 16 + r;
        const int cg = col >> 3, cw = col & 7;
        #pragma unroll
        for (int q = 0; q < 4; ++q) {
            const int b = wv * 16 + kg * 4 + q;
            As[b * 128 + ((cg ^ (b & 7)) * 8) + cw] = bf16_rne(acc[t8][q]);
        }
    }
    // rowsum for b = wv*16 + r (reduce over kg lanes)
    sacc += __shfl_xor(sacc, 16); sacc += __shfl_xor(sacc, 32);
    if (kg == 0) sls[wv * 16 + r] = sacc;

    // w3 slice -> Bs (k3's exact staging)
    #pragma unroll
    for (int p = 0; p < 4; ++p) {
        const int row  = p * 16 + (t >> 4);
        const int gran = t & 15;
        const float* src = w3 + (size_t)(row * 64 + i) * HDIM + gran * 8;
        f32x4 v0 = *(const f32x4*)src;
        f32x4 v1 = *(const f32x4*)(src + 4);
        *(s16x8*)&Bs[row * 128 + ((gran ^ (row & 7)) * 8)] = cvt8(v0, v1);
    }
    if (t < 64) b3s[t] = b3[t * 64 + i];
    __syncthreads();

    // k3's verbatim compute: wave tile [16b x 64o]
    s16x8 bfr[4][4];
    #pragma unroll
    for (int ct = 0; ct < 4; ++ct) {
        const int o = ct * 16 + r;
        #pragma unroll
        for (int ks = 0; ks < 4; ++ks)
            bfr[ct][ks] = *(const s16x8*)&Bs[o * 128 + (((ks * 4 + kg) ^ (o & 7)) * 8)];
    }
    const int bA = wv * 16 + r;
    s16x8 af[4];
    #pragma unroll
    for (int ks = 0; ks < 4; ++ks)
        af[ks] = *(const s16x8*)&As[bA * 128 + (((ks * 4 + kg) ^ (bA & 7)) * 8)];

    f32x4 acc2[4];
    #pragma unroll
    for (int ct = 0; ct < 4; ++ct) { f32x4 z = {0.f,0.f,0.f,0.f}; acc2[ct] = z; }
    #pragma unroll
    for (int ct = 0; ct < 4; ++ct)
        #pragma unroll
        for (int ks = 0; ks < 4; ++ks)
            acc2[ct] = __builtin_amdgcn_mfma_f32_16x16x32_bf16(af[ks], bfr[ct][ks], acc2[ct], 0, 0, 0);

    float* po = part + ((size_t)i * 16 + y8) * 4096;
    #pragma unroll
    for (int ct = 0; ct < 4; ++ct) {
        const int o = ct * 16 + r;
        #pragma unroll
        for (int q = 0; q < 4; ++q) {
            const int b = wv * 16 + kg * 4 + q;
            po[b * 64 + o] = acc2[ct][q] + sls[b] * b3s[o];
        }
    }
}

// ---------------- Kernel 4: wide final reduce over 1024 partials -------------
// 64 blocks x 256 thr; thread (il = t&63, pg = t>>6) sums 256 partials for
// out idx = bid*64 + il (b = bid, o = il); LDS reduce over the 4 p-groups.
__global__ __launch_bounds__(256) void k4_final(
        const float* __restrict__ part, const float* __restrict__ bias,
        float* __restrict__ out) {
    __shared__ float red[4][64];
    const int t  = threadIdx.x;
    const int il = t & 63;
    const int pg = t >> 6;
    const int idx = blockIdx.x * 64 + il;

    float s = 0.f;
    #pragma unroll 8
    for (int p = pg * 256; p < pg * 256 + 256; ++p)
        s += part[(size_t)p * 4096 + idx];
    red[pg][il] = s;
    __syncthreads();
    if (t < 64)
        out[blockIdx.x * 64 + t] = bias[t] + ((red[0][t] + red[1][t]) + (red[2][t] + red[3][t]));
}

extern "C" void kernel_launch(void* const* d_in, const int* in_sizes, int n_in,
                              void* d_out, int out_size, void* d_ws, size_t ws_size,
                              hipStream_t stream) {
    (void)in_sizes; (void)n_in; (void)out_size; (void)ws_size;
    const float* x    = (const float*)d_in[0];
    const float* w1   = (const float*)d_in[1];
    const float* b1   = (const float*)d_in[2];
    const float* w2   = (const float*)d_in[3];
    const float* b2   = (const float*)d_in[4];
    const float* w3   = (const float*)d_in[5];
    const float* b3   = (const float*)d_in[6];
    const float* bias = (const float*)d_in[7];
    float* out = (float*)d_out;

    char* ws = (char*)d_ws;
    unsigned short* h2T = (unsigned short*)ws;                          // 2.10 MB
    const size_t H2T_BYTES = (size_t)(LPOS / 64) * CUNITS * 16;
    float* part = (float*)(ws + H2T_BYTES);                             // 16.8 MB

    k1_siren<<<LPOS / 16, 256, 0, stream>>>(w1, b1, w2, b2, h2T);
    k2_fused<<<dim3(64, KSPLIT), 256, 0, stream>>>(x, h2T, w3, b3, part);
    k4_final<<<64, 256, 0, stream>>>(part, bias, out);
}

// Round 21
// 53.921 us; speedup vs baseline: 1.3832x; 1.1108x over previous
//
#include <hip/hip_runtime.h>
#include <hip/hip_bf16.h>

#define LPOS 8192
#define HDIM 128
#define M_TOT 4096          // B*Cin
#define KSPLIT 16
#define CUNITS 1024                  // 16-B units per 64-k chunk
#define BUNITS (4 * CUNITS)          // 4096 units = 65536 B LDS
#define NPART 1024                   // 64 i x 16 y partials

typedef float  f32x4 __attribute__((ext_vector_type(4)));
typedef short  s16x8 __attribute__((ext_vector_type(8)));
typedef unsigned int u32x4 __attribute__((ext_vector_type(4)));

__device__ __forceinline__ unsigned short bf16_rne(float f) {
    unsigned u = __builtin_bit_cast(unsigned, f);
    u += 0x7fffu + ((u >> 16) & 1u);
    return (unsigned short)(u >> 16);
}
__device__ __forceinline__ float bf16f(unsigned short v) {
    return __builtin_bit_cast(float, (unsigned)v << 16);
}

__device__ __forceinline__ s16x8 cvt8(f32x4 a, f32x4 b) {
    s16x8 r;
    r[0] = (short)bf16_rne(a[0]); r[1] = (short)bf16_rne(a[1]);
    r[2] = (short)bf16_rne(a[2]); r[3] = (short)bf16_rne(a[3]);
    r[4] = (short)bf16_rne(b[0]); r[5] = (short)bf16_rne(b[1]);
    r[6] = (short)bf16_rne(b[2]); r[7] = (short)bf16_rne(b[3]);
    return r;
}

__device__ __forceinline__ float sum8(f32x4 a, f32x4 b) {
    return ((a[0] + a[1]) + (a[2] + a[3])) + ((b[0] + b[1]) + (b[2] + b[3]));
}

// ---------------- Kernel 1: SIREN via MFMA (hi/lo bf16 split) ----------------
// Block (lb, hh): rows l = lb*64..+64, cols h = hh*64..+64 of the h1@w2^T GEMM.
// h1 A-frags computed in-register (sin); w2 staged as hi+lo swizzled bf16;
// 3-term MFMA (HH, HL, LH) keeps f32-equivalent precision (lo*lo ~2^-18 dropped).
__global__ __launch_bounds__(256) void k1_mfma(
        const float* __restrict__ w1, const float* __restrict__ b1,
        const float* __restrict__ w2, const float* __restrict__ b2,
        unsigned short* __restrict__ h2T) {
    __shared__ unsigned short BsH[64 * 128];   // 16 KB  [row][ (gran^(row&7))*8 + jj ]
    __shared__ unsigned short BsL[64 * 128];   // 16 KB
    __shared__ unsigned short Hs[64][72];      // 9 KB   [h_loc][l_loc], 144B rows

    const int t    = threadIdx.x;
    const int lane = t & 63;
    const int wv   = t >> 6;
    const int r    = lane & 15;
    const int kg   = lane >> 4;
    const int lb   = blockIdx.x;     // l-chunk (64 l each)
    const int hh   = blockIdx.y;     // h-half (64 h each)
    const int l0   = lb * 64;

    // ---- stage w2[hh*64 + row][*] as hi/lo bf16, k3's swizzle ----
    #pragma unroll
    for (int p = 0; p < 4; ++p) {
        const int row  = p * 16 + (t >> 4);
        const int gran = t & 15;
        const float* src = w2 + (size_t)(hh * 64 + row) * HDIM + gran * 8;
        f32x4 v0 = *(const f32x4*)src;
        f32x4 v1 = *(const f32x4*)(src + 4);
        s16x8 hi = cvt8(v0, v1);
        f32x4 e0, e1;
        e0[0] = v0[0] - bf16f((unsigned short)hi[0]);
        e0[1] = v0[1] - bf16f((unsigned short)hi[1]);
        e0[2] = v0[2] - bf16f((unsigned short)hi[2]);
        e0[3] = v0[3] - bf16f((unsigned short)hi[3]);
        e1[0] = v1[0] - bf16f((unsigned short)hi[4]);
        e1[1] = v1[1] - bf16f((unsigned short)hi[5]);
        e1[2] = v1[2] - bf16f((unsigned short)hi[6]);
        e1[3] = v1[3] - bf16f((unsigned short)hi[7]);
        s16x8 lo = cvt8(e0, e1);
        *(s16x8*)&BsH[row * 128 + ((gran ^ (row & 7)) * 8)] = hi;
        *(s16x8*)&BsL[row * 128 + ((gran ^ (row & 7)) * 8)] = lo;
    }

    // ---- h1 A-frags in-register: row l = l0 + wv*16 + r ----
    const int lrow = wv * 16 + r;
    const float rel = -1.0f + (2.0f / 8191.0f) * (float)(l0 + lrow);
    s16x8 aH[4], aL[4];
    #pragma unroll
    for (int ks = 0; ks < 4; ++ks) {
        #pragma unroll
        for (int jj = 0; jj < 8; ++jj) {
            const int j = ks * 32 + kg * 8 + jj;
            float v = __sinf(30.0f * (rel * w1[j] + b1[j]));
            unsigned short hi = bf16_rne(v);
            aH[ks][jj] = (short)hi;
            aL[ks][jj] = (short)bf16_rne(v - bf16f(hi));
        }
    }
    __syncthreads();

    // ---- 48 MFMA: acc[ct] over 4 col-tiles x 4 K-steps x {HH,HL,LH} ----
    f32x4 acc[4];
    #pragma unroll
    for (int ct = 0; ct < 4; ++ct) { f32x4 z = {0.f,0.f,0.f,0.f}; acc[ct] = z; }
    #pragma unroll
    for (int ct = 0; ct < 4; ++ct) {
        const int h = ct * 16 + r;
        #pragma unroll
        for (int ks = 0; ks < 4; ++ks) {
            s16x8 bh = *(const s16x8*)&BsH[h * 128 + (((ks * 4 + kg) ^ (h & 7)) * 8)];
            s16x8 bl = *(const s16x8*)&BsL[h * 128 + (((ks * 4 + kg) ^ (h & 7)) * 8)];
            acc[ct] = __builtin_amdgcn_mfma_f32_16x16x32_bf16(aH[ks], bh, acc[ct], 0, 0, 0);
            acc[ct] = __builtin_amdgcn_mfma_f32_16x16x32_bf16(aH[ks], bl, acc[ct], 0, 0, 0);
            acc[ct] = __builtin_amdgcn_mfma_f32_16x16x32_bf16(aL[ks], bh, acc[ct], 0, 0, 0);
        }
    }

    // ---- h2 = sin(30*(acc + b2)) -> Hs transpose tile ----
    // C/D layout: col h = ct*16 + r, row l = wv*16 + kg*4 + q
    #pragma unroll
    for (int ct = 0; ct < 4; ++ct) {
        const int hl = ct * 16 + r;
        const float bb = b2[hh * 64 + hl];
        #pragma unroll
        for (int q = 0; q < 4; ++q) {
            const int ll = wv * 16 + kg * 4 + q;
            Hs[hl][ll] = bf16_rne(__sinf(30.0f * (acc[ct][q] + bb)));
        }
    }
    __syncthreads();

    // ---- write h2T: unit = lb*1024 + k8*128 + (hh*64 + h_loc), 16 B each ----
    #pragma unroll
    for (int p = 0; p < 2; ++p) {
        const int v  = p * 256 + t;
        const int hl = v >> 3;
        const int k8 = v & 7;
        u32x4 u = *(const u32x4*)&Hs[hl][k8 * 8];
        *(u32x4*)(h2T + ((size_t)lb * 1024 + (size_t)k8 * 128 + hh * 64 + hl) * 8) = u;
    }
}

// ---------------- Kernel 2: per-channel GEMM + fused contraction (R20 exact) -
__global__ __launch_bounds__(256, 2) void k2_fused(
        const float* __restrict__ x, const unsigned short* __restrict__ h2T,
        const float* __restrict__ w3, const float* __restrict__ b3,
        float* __restrict__ part) {
    __shared__ __align__(16) char smem[65536];
    unsigned short* lds = (unsigned short*)smem;   // B-stage 64 KB (main loop)

    const int t    = threadIdx.x;
    const int lane = t & 63;
    const int wv   = t >> 6;
    const int r    = lane & 15;
    const int kg   = lane >> 4;
    const int i    = blockIdx.x;     // channel 0..63
    const int y8   = blockIdx.y;     // 0..15
    const int kc   = y8 * 512;

    const float* xp = x + (size_t)((wv * 16 + r) * 64 + i) * LPOS + kc + kg * 8;

    f32x4 xr[2][4];
#define LOADX(SL, IT) do { \
        xr[SL][0] = *(const f32x4*)(xp + (IT) * 64);      \
        xr[SL][1] = *(const f32x4*)(xp + (IT) * 64 + 4);  \
        xr[SL][2] = *(const f32x4*)(xp + (IT) * 64 + 32); \
        xr[SL][3] = *(const f32x4*)(xp + (IT) * 64 + 36); \
    } while (0)

    f32x4 acc[8];
    #pragma unroll
    for (int t8 = 0; t8 < 8; ++t8) { f32x4 z = {0.f,0.f,0.f,0.f}; acc[t8] = z; }
    float sacc = 0.f;

    #pragma unroll 1
    for (int g = 0; g < 2; ++g) {
        const int base = g * 4;
        {
            const unsigned short* src = h2T + (size_t)(y8 * 2 + g) * (BUNITS * 8);
            #pragma unroll
            for (int j = 0; j < 16; ++j) {
                const int U = j * 256 + t;
                __builtin_amdgcn_global_load_lds(
                    (const unsigned int*)(src + (size_t)U * 8),
                    (unsigned int*)&lds[U * 8], 16, 0, 0);
            }
        }
        LOADX(0, base); LOADX(1, base + 1);
        __syncthreads();

        #pragma unroll
        for (int it = 0; it < 4; ++it) {
            const int sl = it & 1;
            s16x8 alo = cvt8(xr[sl][0], xr[sl][1]);
            s16x8 ahi = cvt8(xr[sl][2], xr[sl][3]);
            sacc += sum8(xr[sl][0], xr[sl][1]) + sum8(xr[sl][2], xr[sl][3]);
            if (it + 2 < 4) LOADX(sl, base + it + 2);

            #pragma unroll
            for (int t8 = 0; t8 < 8; ++t8) {
                s16x8 blo = *(const s16x8*)&lds[((size_t)it * CUNITS + kg * 128 + t8 * 16 + r) * 8];
                s16x8 bhi = *(const s16x8*)&lds[((size_t)it * CUNITS + (kg + 4) * 128 + t8 * 16 + r) * 8];
                acc[t8] = __builtin_amdgcn_mfma_f32_16x16x32_bf16(alo, blo, acc[t8], 0, 0, 0);
                acc[t8] = __builtin_amdgcn_mfma_f32_16x16x32_bf16(ahi, bhi, acc[t8], 0, 0, 0);
            }
        }
        __syncthreads();
    }
#undef LOADX

    unsigned short* As = (unsigned short*)smem;            // [64][128] bf16 swz
    unsigned short* Bs = (unsigned short*)(smem + 16384);  // w3 [64o][128h] swz
    float* b3s = (float*)(smem + 32768);
    float* sls = (float*)(smem + 33024);

    #pragma unroll
    for (int t8 = 0; t8 < 8; ++t8) {
        const int col = t8 * 16 + r;
        const int cg = col >> 3, cw = col & 7;
        #pragma unroll
        for (int q = 0; q < 4; ++q) {
            const int b = wv * 16 + kg * 4 + q;
            As[b * 128 + ((cg ^ (b & 7)) * 8) + cw] = bf16_rne(acc[t8][q]);
        }
    }
    sacc += __shfl_xor(sacc, 16); sacc += __shfl_xor(sacc, 32);
    if (kg == 0) sls[wv * 16 + r] = sacc;

    #pragma unroll
    for (int p = 0; p < 4; ++p) {
        const int row  = p * 16 + (t >> 4);
        const int gran = t & 15;
        const float* src = w3 + (size_t)(row * 64 + i) * HDIM + gran * 8;
        f32x4 v0 = *(const f32x4*)src;
        f32x4 v1 = *(const f32x4*)(src + 4);
        *(s16x8*)&Bs[row * 128 + ((gran ^ (row & 7)) * 8)] = cvt8(v0, v1);
    }
    if (t < 64) b3s[t] = b3[t * 64 + i];
    __syncthreads();

    s16x8 bfr[4][4];
    #pragma unroll
    for (int ct = 0; ct < 4; ++ct) {
        const int o = ct * 16 + r;
        #pragma unroll
        for (int ks = 0; ks < 4; ++ks)
            bfr[ct][ks] = *(const s16x8*)&Bs[o * 128 + (((ks * 4 + kg) ^ (o & 7)) * 8)];
    }
    const int bA = wv * 16 + r;
    s16x8 af[4];
    #pragma unroll
    for (int ks = 0; ks < 4; ++ks)
        af[ks] = *(const s16x8*)&As[bA * 128 + (((ks * 4 + kg) ^ (bA & 7)) * 8)];

    f32x4 acc2[4];
    #pragma unroll
    for (int ct = 0; ct < 4; ++ct) { f32x4 z = {0.f,0.f,0.f,0.f}; acc2[ct] = z; }
    #pragma unroll
    for (int ct = 0; ct < 4; ++ct)
        #pragma unroll
        for (int ks = 0; ks < 4; ++ks)
            acc2[ct] = __builtin_amdgcn_mfma_f32_16x16x32_bf16(af[ks], bfr[ct][ks], acc2[ct], 0, 0, 0);

    float* po = part + ((size_t)i * 16 + y8) * 4096;
    #pragma unroll
    for (int ct = 0; ct < 4; ++ct) {
        const int o = ct * 16 + r;
        #pragma unroll
        for (int q = 0; q < 4; ++q) {
            const int b = wv * 16 + kg * 4 + q;
            po[b * 64 + o] = acc2[ct][q] + sls[b] * b3s[o];
        }
    }
}

// ---------------- Kernel 4: wide final reduce (R20 exact) --------------------
__global__ __launch_bounds__(256) void k4_final(
        const float* __restrict__ part, const float* __restrict__ bias,
        float* __restrict__ out) {
    __shared__ float red[4][64];
    const int t  = threadIdx.x;
    const int il = t & 63;
    const int pg = t >> 6;
    const int idx = blockIdx.x * 64 + il;

    float s = 0.f;
    #pragma unroll 8
    for (int p = pg * 256; p < pg * 256 + 256; ++p)
        s += part[(size_t)p * 4096 + idx];
    red[pg][il] = s;
    __syncthreads();
    if (t < 64)
        out[blockIdx.x * 64 + t] = bias[t] + ((red[0][t] + red[1][t]) + (red[2][t] + red[3][t]));
}

extern "C" void kernel_launch(void* const* d_in, const int* in_sizes, int n_in,
                              void* d_out, int out_size, void* d_ws, size_t ws_size,
                              hipStream_t stream) {
    (void)in_sizes; (void)n_in; (void)out_size; (void)ws_size;
    const float* x    = (const float*)d_in[0];
    const float* w1   = (const float*)d_in[1];
    const float* b1   = (const float*)d_in[2];
    const float* w2   = (const float*)d_in[3];
    const float* b2   = (const float*)d_in[4];
    const float* w3   = (const float*)d_in[5];
    const float* b3   = (const float*)d_in[6];
    const float* bias = (const float*)d_in[7];
    float* out = (float*)d_out;

    char* ws = (char*)d_ws;
    unsigned short* h2T = (unsigned short*)ws;                          // 2.10 MB
    const size_t H2T_BYTES = (size_t)(LPOS / 64) * CUNITS * 16;
    float* part = (float*)(ws + H2T_BYTES);                             // 16.8 MB

    k1_mfma<<<dim3(128, 2), 256, 0, stream>>>(w1, b1, w2, b2, h2T);
    k2_fused<<<dim3(64, KSPLIT), 256, 0, stream>>>(x, h2T, w3, b3, part);
    k4_final<<<64, 256, 0, stream>>>(part, bias, out);
}

// Round 22
// 53.195 us; speedup vs baseline: 1.4021x; 1.0136x over previous
//
#include <hip/hip_runtime.h>
#include <hip/hip_bf16.h>

#define LPOS 8192
#define HDIM 128
#define M_TOT 4096          // B*Cin
#define KSPLIT 16
#define CUNITS 1024                  // 16-B units per 64-k chunk
#define NPART 1024                   // 64 i x 16 y partials

typedef float  f32x4 __attribute__((ext_vector_type(4)));
typedef short  s16x8 __attribute__((ext_vector_type(8)));
typedef unsigned int u32x4 __attribute__((ext_vector_type(4)));

__device__ __forceinline__ unsigned short bf16_rne(float f) {
    unsigned u = __builtin_bit_cast(unsigned, f);
    u += 0x7fffu + ((u >> 16) & 1u);
    return (unsigned short)(u >> 16);
}
__device__ __forceinline__ float bf16f(unsigned short v) {
    return __builtin_bit_cast(float, (unsigned)v << 16);
}

__device__ __forceinline__ s16x8 cvt8(f32x4 a, f32x4 b) {
    s16x8 r;
    r[0] = (short)bf16_rne(a[0]); r[1] = (short)bf16_rne(a[1]);
    r[2] = (short)bf16_rne(a[2]); r[3] = (short)bf16_rne(a[3]);
    r[4] = (short)bf16_rne(b[0]); r[5] = (short)bf16_rne(b[1]);
    r[6] = (short)bf16_rne(b[2]); r[7] = (short)bf16_rne(b[3]);
    return r;
}

__device__ __forceinline__ float sum8(f32x4 a, f32x4 b) {
    return ((a[0] + a[1]) + (a[2] + a[3])) + ((b[0] + b[1]) + (b[2] + b[3]));
}

// ---------------- Kernel 1: SIREN via MFMA (R21 exact) -----------------------
__global__ __launch_bounds__(256) void k1_mfma(
        const float* __restrict__ w1, const float* __restrict__ b1,
        const float* __restrict__ w2, const float* __restrict__ b2,
        unsigned short* __restrict__ h2T) {
    __shared__ unsigned short BsH[64 * 128];   // 16 KB
    __shared__ unsigned short BsL[64 * 128];   // 16 KB
    __shared__ unsigned short Hs[64][72];      // 9 KB

    const int t    = threadIdx.x;
    const int lane = t & 63;
    const int wv   = t >> 6;
    const int r    = lane & 15;
    const int kg   = lane >> 4;
    const int lb   = blockIdx.x;     // l-chunk (64 l each)
    const int hh   = blockIdx.y;     // h-half (64 h each)
    const int l0   = lb * 64;

    #pragma unroll
    for (int p = 0; p < 4; ++p) {
        const int row  = p * 16 + (t >> 4);
        const int gran = t & 15;
        const float* src = w2 + (size_t)(hh * 64 + row) * HDIM + gran * 8;
        f32x4 v0 = *(const f32x4*)src;
        f32x4 v1 = *(const f32x4*)(src + 4);
        s16x8 hi = cvt8(v0, v1);
        f32x4 e0, e1;
        e0[0] = v0[0] - bf16f((unsigned short)hi[0]);
        e0[1] = v0[1] - bf16f((unsigned short)hi[1]);
        e0[2] = v0[2] - bf16f((unsigned short)hi[2]);
        e0[3] = v0[3] - bf16f((unsigned short)hi[3]);
        e1[0] = v1[0] - bf16f((unsigned short)hi[4]);
        e1[1] = v1[1] - bf16f((unsigned short)hi[5]);
        e1[2] = v1[2] - bf16f((unsigned short)hi[6]);
        e1[3] = v1[3] - bf16f((unsigned short)hi[7]);
        s16x8 lo = cvt8(e0, e1);
        *(s16x8*)&BsH[row * 128 + ((gran ^ (row & 7)) * 8)] = hi;
        *(s16x8*)&BsL[row * 128 + ((gran ^ (row & 7)) * 8)] = lo;
    }

    const int lrow = wv * 16 + r;
    const float rel = -1.0f + (2.0f / 8191.0f) * (float)(l0 + lrow);
    s16x8 aH[4], aL[4];
    #pragma unroll
    for (int ks = 0; ks < 4; ++ks) {
        #pragma unroll
        for (int jj = 0; jj < 8; ++jj) {
            const int j = ks * 32 + kg * 8 + jj;
            float v = __sinf(30.0f * (rel * w1[j] + b1[j]));
            unsigned short hi = bf16_rne(v);
            aH[ks][jj] = (short)hi;
            aL[ks][jj] = (short)bf16_rne(v - bf16f(hi));
        }
    }
    __syncthreads();

    f32x4 acc[4];
    #pragma unroll
    for (int ct = 0; ct < 4; ++ct) { f32x4 z = {0.f,0.f,0.f,0.f}; acc[ct] = z; }
    #pragma unroll
    for (int ct = 0; ct < 4; ++ct) {
        const int h = ct * 16 + r;
        #pragma unroll
        for (int ks = 0; ks < 4; ++ks) {
            s16x8 bh = *(const s16x8*)&BsH[h * 128 + (((ks * 4 + kg) ^ (h & 7)) * 8)];
            s16x8 bl = *(const s16x8*)&BsL[h * 128 + (((ks * 4 + kg) ^ (h & 7)) * 8)];
            acc[ct] = __builtin_amdgcn_mfma_f32_16x16x32_bf16(aH[ks], bh, acc[ct], 0, 0, 0);
            acc[ct] = __builtin_amdgcn_mfma_f32_16x16x32_bf16(aH[ks], bl, acc[ct], 0, 0, 0);
            acc[ct] = __builtin_amdgcn_mfma_f32_16x16x32_bf16(aL[ks], bh, acc[ct], 0, 0, 0);
        }
    }

    #pragma unroll
    for (int ct = 0; ct < 4; ++ct) {
        const int hl = ct * 16 + r;
        const float bb = b2[hh * 64 + hl];
        #pragma unroll
        for (int q = 0; q < 4; ++q) {
            const int ll = wv * 16 + kg * 4 + q;
            Hs[hl][ll] = bf16_rne(__sinf(30.0f * (acc[ct][q] + bb)));
        }
    }
    __syncthreads();

    #pragma unroll
    for (int p = 0; p < 2; ++p) {
        const int v  = p * 256 + t;
        const int hl = v >> 3;
        const int k8 = v & 7;
        u32x4 u = *(const u32x4*)&Hs[hl][k8 * 8];
        *(u32x4*)(h2T + ((size_t)lb * 1024 + (size_t)k8 * 128 + hh * 64 + hl) * 8) = u;
    }
}

// ---------------- Kernel 2: per-channel GEMM + fused contraction -------------
// R21 math; staging now 2 chunks (32 KB) x 4 rounds -> LDS footprint 33.3 KB
// -> 4 blocks/CU (was 2): stage/x latency cross-hides between blocks.
__global__ __launch_bounds__(256, 2) void k2_fused(
        const float* __restrict__ x, const unsigned short* __restrict__ h2T,
        const float* __restrict__ w3, const float* __restrict__ b3,
        float* __restrict__ part) {
    __shared__ __align__(16) char smem[33280];
    unsigned short* lds = (unsigned short*)smem;   // B-stage 32 KB (main loop)

    const int t    = threadIdx.x;
    const int lane = t & 63;
    const int wv   = t >> 6;
    const int r    = lane & 15;
    const int kg   = lane >> 4;
    const int i    = blockIdx.x;     // channel 0..63
    const int y8   = blockIdx.y;     // 0..15
    const int kc   = y8 * 512;

    const float* xp = x + (size_t)((wv * 16 + r) * 64 + i) * LPOS + kc + kg * 8;

    f32x4 xr[2][4];
#define LOADX(SL, IT) do { \
        xr[SL][0] = *(const f32x4*)(xp + (IT) * 64);      \
        xr[SL][1] = *(const f32x4*)(xp + (IT) * 64 + 4);  \
        xr[SL][2] = *(const f32x4*)(xp + (IT) * 64 + 32); \
        xr[SL][3] = *(const f32x4*)(xp + (IT) * 64 + 36); \
    } while (0)

    f32x4 acc[8];
    #pragma unroll
    for (int t8 = 0; t8 < 8; ++t8) { f32x4 z = {0.f,0.f,0.f,0.f}; acc[t8] = z; }
    float sacc = 0.f;

    #pragma unroll 1
    for (int g = 0; g < 4; ++g) {          // 4 rounds x 2 chunks (128 k each)
        const int base = g * 2;
        {   // stage 2 chunks = 2048 units, 8 issues/thread
            const unsigned short* src = h2T + (size_t)(y8 * 8 + g * 2) * (CUNITS * 8);
            #pragma unroll
            for (int j = 0; j < 8; ++j) {
                const int U = j * 256 + t;
                __builtin_amdgcn_global_load_lds(
                    (const unsigned int*)(src + (size_t)U * 8),
                    (unsigned int*)&lds[U * 8], 16, 0, 0);
            }
        }
        LOADX(0, base); LOADX(1, base + 1);
        __syncthreads();                   // B staged; x0/x1 in flight or landed

        #pragma unroll
        for (int it = 0; it < 2; ++it) {
            const int sl = it & 1;
            s16x8 alo = cvt8(xr[sl][0], xr[sl][1]);
            s16x8 ahi = cvt8(xr[sl][2], xr[sl][3]);
            sacc += sum8(xr[sl][0], xr[sl][1]) + sum8(xr[sl][2], xr[sl][3]);

            #pragma unroll
            for (int t8 = 0; t8 < 8; ++t8) {
                s16x8 blo = *(const s16x8*)&lds[((size_t)it * CUNITS + kg * 128 + t8 * 16 + r) * 8];
                s16x8 bhi = *(const s16x8*)&lds[((size_t)it * CUNITS + (kg + 4) * 128 + t8 * 16 + r) * 8];
                acc[t8] = __builtin_amdgcn_mfma_f32_16x16x32_bf16(alo, blo, acc[t8], 0, 0, 0);
                acc[t8] = __builtin_amdgcn_mfma_f32_16x16x32_bf16(ahi, bhi, acc[t8], 0, 0, 0);
            }
        }
        __syncthreads();                   // B(g) reads done before restage
    }
#undef LOADX

    unsigned short* As = (unsigned short*)smem;            // [64][128] bf16 swz
    unsigned short* Bs = (unsigned short*)(smem + 16384);  // w3 [64o][128h] swz
    float* b3s = (float*)(smem + 32768);
    float* sls = (float*)(smem + 33024);

    #pragma unroll
    for (int t8 = 0; t8 < 8; ++t8) {
        const int col = t8 * 16 + r;
        const int cg = col >> 3, cw = col & 7;
        #pragma unroll
        for (int q = 0; q < 4; ++q) {
            const int b = wv * 16 + kg * 4 + q;
            As[b * 128 + ((cg ^ (b & 7)) * 8) + cw] = bf16_rne(acc[t8][q]);
        }
    }
    sacc += __shfl_xor(sacc, 16); sacc += __shfl_xor(sacc, 32);
    if (kg == 0) sls[wv * 16 + r] = sacc;

    #pragma unroll
    for (int p = 0; p < 4; ++p) {
        const int row  = p * 16 + (t >> 4);
        const int gran = t & 15;
        const float* src = w3 + (size_t)(row * 64 + i) * HDIM + gran * 8;
        f32x4 v0 = *(const f32x4*)src;
        f32x4 v1 = *(const f32x4*)(src + 4);
        *(s16x8*)&Bs[row * 128 + ((gran ^ (row & 7)) * 8)] = cvt8(v0, v1);
    }
    if (t < 64) b3s[t] = b3[t * 64 + i];
    __syncthreads();

    s16x8 bfr[4][4];
    #pragma unroll
    for (int ct = 0; ct < 4; ++ct) {
        const int o = ct * 16 + r;
        #pragma unroll
        for (int ks = 0; ks < 4; ++ks)
            bfr[ct][ks] = *(const s16x8*)&Bs[o * 128 + (((ks * 4 + kg) ^ (o & 7)) * 8)];
    }
    const int bA = wv * 16 + r;
    s16x8 af[4];
    #pragma unroll
    for (int ks = 0; ks < 4; ++ks)
        af[ks] = *(const s16x8*)&As[bA * 128 + (((ks * 4 + kg) ^ (bA & 7)) * 8)];

    f32x4 acc2[4];
    #pragma unroll
    for (int ct = 0; ct < 4; ++ct) { f32x4 z = {0.f,0.f,0.f,0.f}; acc2[ct] = z; }
    #pragma unroll
    for (int ct = 0; ct < 4; ++ct)
        #pragma unroll
        for (int ks = 0; ks < 4; ++ks)
            acc2[ct] = __builtin_amdgcn_mfma_f32_16x16x32_bf16(af[ks], bfr[ct][ks], acc2[ct], 0, 0, 0);

    float* po = part + ((size_t)i * 16 + y8) * 4096;
    #pragma unroll
    for (int ct = 0; ct < 4; ++ct) {
        const int o = ct * 16 + r;
        #pragma unroll
        for (int q = 0; q < 4; ++q) {
            const int b = wv * 16 + kg * 4 + q;
            po[b * 64 + o] = acc2[ct][q] + sls[b] * b3s[o];
        }
    }
}

// ---------------- Kernel 4: wide final reduce (R21 exact) --------------------
__global__ __launch_bounds__(256) void k4_final(
        const float* __restrict__ part, const float* __restrict__ bias,
        float* __restrict__ out) {
    __shared__ float red[4][64];
    const int t  = threadIdx.x;
    const int il = t & 63;
    const int pg = t >> 6;
    const int idx = blockIdx.x * 64 + il;

    float s = 0.f;
    #pragma unroll 8
    for (int p = pg * 256; p < pg * 256 + 256; ++p)
        s += part[(size_t)p * 4096 + idx];
    red[pg][il] = s;
    __syncthreads();
    if (t < 64)
        out[blockIdx.x * 64 + t] = bias[t] + ((red[0][t] + red[1][t]) + (red[2][t] + red[3][t]));
}

extern "C" void kernel_launch(void* const* d_in, const int* in_sizes, int n_in,
                              void* d_out, int out_size, void* d_ws, size_t ws_size,
                              hipStream_t stream) {
    (void)in_sizes; (void)n_in; (void)out_size; (void)ws_size;
    const float* x    = (const float*)d_in[0];
    const float* w1   = (const float*)d_in[1];
    const float* b1   = (const float*)d_in[2];
    const float* w2   = (const float*)d_in[3];
    const float* b2   = (const float*)d_in[4];
    const float* w3   = (const float*)d_in[5];
    const float* b3   = (const float*)d_in[6];
    const float* bias = (const float*)d_in[7];
    float* out = (float*)d_out;

    char* ws = (char*)d_ws;
    unsigned short* h2T = (unsigned short*)ws;                          // 2.10 MB
    const size_t H2T_BYTES = (size_t)(LPOS / 64) * CUNITS * 16;
    float* part = (float*)(ws + H2T_BYTES);                             // 16.8 MB

    k1_mfma<<<dim3(128, 2), 256, 0, stream>>>(w1, b1, w2, b2, h2T);
    k2_fused<<<dim3(64, KSPLIT), 256, 0, stream>>>(x, h2T, w3, b3, part);
    k4_final<<<64, 256, 0, stream>>>(part, bias, out);
}